// Round 1
// baseline (1298.311 us; speedup 1.0000x reference)
//
#include <hip/hip_runtime.h>
#include <math.h>

#define N_NODES   100000
#define N_EDGES   1250000
#define HID       64
#define N_RBF     32
#define N_GRAPHS  512
#define N_EXPERTS 8
#define N_LAYERS  3
#define CUTOFF    6.0f
#define GATE_IN   72
#define G1_DIM    64
#define G2_DIM    32
#define K_TAB     4096   // lerp intervals; table has K_TAB+1 points

// ---------------------------------------------------------------------------
// Filter table: f_i(w) = silu(rbf(w) @ fW1[i]^T + fb1[i]) @ fW2[i]^T + fb2[i]
// One block (64 threads) per (layer, grid point).
// ---------------------------------------------------------------------------
__global__ __launch_bounds__(64) void build_tab(
    const float* __restrict__ fW1, const float* __restrict__ fb1,
    const float* __restrict__ fW2, const float* __restrict__ fb2,
    float* __restrict__ tab) {
  int b = blockIdx.x;                 // 3 * (K_TAB+1)
  int layer = b / (K_TAB + 1);
  int k = b % (K_TAB + 1);
  int t = threadIdx.x;                // 0..63
  __shared__ float rbf[N_RBF];
  __shared__ float h1[HID];

  float w = (CUTOFF / (float)K_TAB) * (float)k;
  const float delta = CUTOFF / (float)(N_RBF - 1);
  const float coeff = -0.5f / (delta * delta);
  if (t < N_RBF) {
    float d = w - delta * (float)t;
    rbf[t] = expf(coeff * d * d);
  }
  __syncthreads();

  const float* W1 = fW1 + (layer * HID + t) * N_RBF;
  float s = fb1[layer * HID + t];
#pragma unroll
  for (int j = 0; j < N_RBF; j++) s += rbf[j] * W1[j];
  float sig = 1.0f / (1.0f + expf(-s));
  h1[t] = s * sig;
  __syncthreads();

  const float* W2 = fW2 + (layer * HID + t) * HID;
  float f = fb2[layer * HID + t];
#pragma unroll
  for (int c = 0; c < HID; c++) f += h1[c] * W2[c];
  tab[(layer * (K_TAB + 1) + k) * HID + t] = f;
}

// ---------------------------------------------------------------------------
// x[n][h] = emb[z[n]][h]
// ---------------------------------------------------------------------------
__global__ __launch_bounds__(256) void embed_kernel(
    const int* __restrict__ z, const float* __restrict__ emb,
    float* __restrict__ x) {
  int i = blockIdx.x * 256 + threadIdx.x;
  if (i < N_NODES * HID) {
    int n = i >> 6, h = i & 63;
    x[i] = emb[z[n] * HID + h];
  }
}

// ---------------------------------------------------------------------------
// y[n][o] = sum_c x[n][c] * W[o][c] + b[o]   (64x64 dense, 64 rows / block)
// ---------------------------------------------------------------------------
__global__ __launch_bounds__(256) void dense64(
    const float* __restrict__ x, const float* __restrict__ W,
    const float* __restrict__ b, float* __restrict__ y) {
  __shared__ float xs[64][64];
  __shared__ float Ws[64][68];   // pad to 68 floats: 272B rows, 16B aligned
  int t = threadIdx.x;
  int row0 = blockIdx.x * 64;

  for (int i = t; i < 4096; i += 256) Ws[i >> 6][i & 63] = W[i];
  for (int i = t; i < 4096; i += 256) {
    int r = i >> 6, gr = row0 + r;
    xs[r][i & 63] = (gr < N_NODES) ? x[gr * 64 + (i & 63)] : 0.0f;
  }
  __syncthreads();

  int l = t & 63, q = t >> 6;
  float acc[16];
  float bl = b[l];
#pragma unroll
  for (int rr = 0; rr < 16; rr++) acc[rr] = bl;
  for (int c4 = 0; c4 < 16; c4++) {
    float4 wv = *(const float4*)&Ws[l][c4 * 4];
#pragma unroll
    for (int rr = 0; rr < 16; rr++) {
      float4 xv = *(const float4*)&xs[q * 16 + rr][c4 * 4];
      acc[rr] += xv.x * wv.x + xv.y * wv.y + xv.z * wv.z + xv.w * wv.w;
    }
  }
#pragma unroll
  for (int rr = 0; rr < 16; rr++) {
    int gr = row0 + q * 16 + rr;
    if (gr < N_NODES) y[gr * 64 + l] = acc[rr];
  }
}

// ---------------------------------------------------------------------------
// x[n] += silu(agg[n] @ W1^T + b1) @ W2^T + b2    (64 rows / block)
// ---------------------------------------------------------------------------
__global__ __launch_bounds__(256) void update64(
    const float* __restrict__ agg,
    const float* __restrict__ W1, const float* __restrict__ b1,
    const float* __restrict__ W2, const float* __restrict__ b2,
    float* __restrict__ x) {
  __shared__ float as[64][64];   // agg tile, then reused as h tile
  __shared__ float W1s[64][68];
  __shared__ float W2s[64][68];
  int t = threadIdx.x;
  int row0 = blockIdx.x * 64;

  for (int i = t; i < 4096; i += 256) {
    W1s[i >> 6][i & 63] = W1[i];
    W2s[i >> 6][i & 63] = W2[i];
  }
  for (int i = t; i < 4096; i += 256) {
    int r = i >> 6, gr = row0 + r;
    as[r][i & 63] = (gr < N_NODES) ? agg[gr * 64 + (i & 63)] : 0.0f;
  }
  __syncthreads();

  int l = t & 63, q = t >> 6;
  float acc[16];
  {
    float bl = b1[l];
#pragma unroll
    for (int rr = 0; rr < 16; rr++) acc[rr] = bl;
    for (int c4 = 0; c4 < 16; c4++) {
      float4 wv = *(const float4*)&W1s[l][c4 * 4];
#pragma unroll
      for (int rr = 0; rr < 16; rr++) {
        float4 xv = *(const float4*)&as[q * 16 + rr][c4 * 4];
        acc[rr] += xv.x * wv.x + xv.y * wv.y + xv.z * wv.z + xv.w * wv.w;
      }
    }
  }
  __syncthreads();  // all reads of `as` done
#pragma unroll
  for (int rr = 0; rr < 16; rr++) {
    float s = acc[rr];
    float sig = 1.0f / (1.0f + expf(-s));
    as[q * 16 + rr][l] = s * sig;   // h tile
  }
  __syncthreads();
  {
    float bl = b2[l];
#pragma unroll
    for (int rr = 0; rr < 16; rr++) acc[rr] = bl;
    for (int c4 = 0; c4 < 16; c4++) {
      float4 wv = *(const float4*)&W2s[l][c4 * 4];
#pragma unroll
      for (int rr = 0; rr < 16; rr++) {
        float4 xv = *(const float4*)&as[q * 16 + rr][c4 * 4];
        acc[rr] += xv.x * wv.x + xv.y * wv.y + xv.z * wv.z + xv.w * wv.w;
      }
    }
#pragma unroll
    for (int rr = 0; rr < 16; rr++) {
      int gr = row0 + q * 16 + rr;
      if (gr < N_NODES) x[gr * 64 + l] += acc[rr];
    }
  }
}

// ---------------------------------------------------------------------------
// Edge scatter: agg[dst] += y[src] * lerp(tab, w).  One wave per edge chunk,
// lane = channel.  Contiguous edge ranges per wave for index-load locality.
// ---------------------------------------------------------------------------
__global__ __launch_bounds__(256) void edge_kernel(
    const int* __restrict__ src, const int* __restrict__ dst,
    const float* __restrict__ ew, const float* __restrict__ tab,
    const float* __restrict__ y, float* __restrict__ agg) {
  int wid = (blockIdx.x * 256 + threadIdx.x) >> 6;
  int lane = threadIdx.x & 63;
  int nw = (gridDim.x * 256) >> 6;
  int epw = (N_EDGES + nw - 1) / nw;
  int e0 = wid * epw;
  int e1 = e0 + epw; if (e1 > N_EDGES) e1 = N_EDGES;
  const float inv = (float)K_TAB / CUTOFF;
  for (int e = e0; e < e1; e++) {
    int s = src[e], d = dst[e];
    float u = ew[e] * inv;
    int idx = (int)u;
    if (idx > K_TAB - 1) idx = K_TAB - 1;
    float fr = u - (float)idx;
    float f0 = tab[idx * 64 + lane];
    float f1 = tab[idx * 64 + 64 + lane];
    float f = f0 + (f1 - f0) * fr;
    unsafeAtomicAdd(&agg[d * 64 + lane], y[s * 64 + lane] * f);
  }
}

// ---------------------------------------------------------------------------
// Mean-pool prep: batch is sorted; each wave handles 64 contiguous nodes and
// emits one atomic per (segment run, channel).
// ---------------------------------------------------------------------------
__global__ __launch_bounds__(256) void pool_kernel(
    const float* __restrict__ x, const int* __restrict__ batch,
    float* __restrict__ pooled, float* __restrict__ counts) {
  int wid = (blockIdx.x * 256 + threadIdx.x) >> 6;
  int lane = threadIdx.x & 63;
  int n0 = wid * 64;
  if (n0 >= N_NODES) return;
  int n1 = n0 + 64; if (n1 > N_NODES) n1 = N_NODES;
  int curg = batch[n0];
  float acc = 0.0f, cnt = 0.0f;
  for (int n = n0; n < n1; n++) {
    int g = batch[n];
    if (g != curg) {
      unsafeAtomicAdd(&pooled[curg * 64 + lane], acc);
      if (lane == 0) unsafeAtomicAdd(&counts[curg], cnt);
      curg = g; acc = 0.0f; cnt = 0.0f;
    }
    acc += x[n * 64 + lane];
    cnt += 1.0f;
  }
  unsafeAtomicAdd(&pooled[curg * 64 + lane], acc);
  if (lane == 0) unsafeAtomicAdd(&counts[curg], cnt);
}

// ---------------------------------------------------------------------------
// Gate MLP + softmax + prediction.  One wave per graph, 4 graphs / block.
// out: logits[512*8] | weights[512*8] | prediction[512]
// ---------------------------------------------------------------------------
__global__ __launch_bounds__(256) void gate_kernel(
    const float* __restrict__ pooled, const float* __restrict__ counts,
    const float* __restrict__ mlip,
    const float* __restrict__ gW1, const float* __restrict__ gb1,
    const float* __restrict__ gW2, const float* __restrict__ gb2,
    const float* __restrict__ gW3, const float* __restrict__ gb3,
    float* __restrict__ out) {
  __shared__ float ins[4][GATE_IN];
  __shared__ float h1s[4][G1_DIM];
  __shared__ float h2s[4][G2_DIM];
  __shared__ float lg[4][N_EXPERTS];
  int wv = threadIdx.x >> 6, lane = threadIdx.x & 63;
  int g = blockIdx.x * 4 + wv;   // grid is exactly 128 blocks -> g < 512

  float cnt = counts[g];
  if (cnt < 1.0f) cnt = 1.0f;
  ins[wv][lane] = pooled[g * 64 + lane] / cnt;
  if (lane < N_EXPERTS) ins[wv][64 + lane] = mlip[g * N_EXPERTS + lane];
  __syncthreads();

  {
    float s = gb1[lane];
    for (int c = 0; c < GATE_IN; c++) s += ins[wv][c] * gW1[lane * GATE_IN + c];
    h1s[wv][lane] = fmaxf(s, 0.0f);
  }
  __syncthreads();
  if (lane < G2_DIM) {
    float s = gb2[lane];
    for (int c = 0; c < G1_DIM; c++) s += h1s[wv][c] * gW2[lane * G1_DIM + c];
    h2s[wv][lane] = fmaxf(s, 0.0f);
  }
  __syncthreads();
  if (lane < N_EXPERTS) {
    float s = gb3[lane];
    for (int c = 0; c < G2_DIM; c++) s += h2s[wv][c] * gW3[lane * G2_DIM + c];
    lg[wv][lane] = s;
  }
  __syncthreads();
  if (lane < N_EXPERTS) {
    float m = -1e30f;
    for (int j = 0; j < N_EXPERTS; j++) m = fmaxf(m, lg[wv][j]);
    float den = 0.0f;
    for (int j = 0; j < N_EXPERTS; j++) den += expf(lg[wv][j] - m);
    float wgt = expf(lg[wv][lane] - m) / den;
    out[g * 8 + lane] = lg[wv][lane];
    out[N_GRAPHS * 8 + g * 8 + lane] = wgt;
    if (lane == 0) {
      float p = 0.0f;
      for (int j = 0; j < N_EXPERTS; j++)
        p += mlip[g * 8 + j] * expf(lg[wv][j] - m) / den;
      out[N_GRAPHS * 16 + g] = p;
    }
  }
}

// ---------------------------------------------------------------------------
extern "C" void kernel_launch(void* const* d_in, const int* in_sizes, int n_in,
                              void* d_out, int out_size, void* d_ws, size_t ws_size,
                              hipStream_t stream) {
  const int*   z     = (const int*)  d_in[0];
  const int*   ei    = (const int*)  d_in[1];
  const float* ew    = (const float*)d_in[2];
  const int*   batch = (const int*)  d_in[3];
  const float* mlip  = (const float*)d_in[4];
  const float* emb   = (const float*)d_in[5];
  const float* fW1   = (const float*)d_in[6];
  const float* fb1   = (const float*)d_in[7];
  const float* fW2   = (const float*)d_in[8];
  const float* fb2   = (const float*)d_in[9];
  const float* dW    = (const float*)d_in[10];
  const float* db    = (const float*)d_in[11];
  const float* uW1   = (const float*)d_in[12];
  const float* ub1   = (const float*)d_in[13];
  const float* uW2   = (const float*)d_in[14];
  const float* ub2   = (const float*)d_in[15];
  const float* gW1   = (const float*)d_in[16];
  const float* gb1   = (const float*)d_in[17];
  const float* gW2   = (const float*)d_in[18];
  const float* gb2   = (const float*)d_in[19];
  const float* gW3   = (const float*)d_in[20];
  const float* gb3   = (const float*)d_in[21];

  const int* src = ei;
  const int* dst = ei + N_EDGES;

  float* ws = (float*)d_ws;
  float* x      = ws;                       // 6,400,000
  float* y      = ws + 6400000;             // 6,400,000
  float* agg    = ws + 12800000;            // 6,400,000
  float* tab    = ws + 19200000;            // 3*4097*64 = 786,624
  float* pooled = ws + 19986624;            // 32,768
  float* counts = ws + 20019392;            // 512   (contiguous with pooled)

  build_tab<<<N_LAYERS * (K_TAB + 1), 64, 0, stream>>>(fW1, fb1, fW2, fb2, tab);
  embed_kernel<<<(N_NODES * HID + 255) / 256, 256, 0, stream>>>(z, emb, x);

  for (int i = 0; i < N_LAYERS; i++) {
    dense64<<<(N_NODES + 63) / 64, 256, 0, stream>>>(x, dW + i * 4096, db + i * 64, y);
    hipMemsetAsync(agg, 0, (size_t)N_NODES * HID * sizeof(float), stream);
    edge_kernel<<<2048, 256, 0, stream>>>(src, dst, ew, tab + i * (K_TAB + 1) * 64, y, agg);
    update64<<<(N_NODES + 63) / 64, 256, 0, stream>>>(agg, uW1 + i * 4096, ub1 + i * 64,
                                                      uW2 + i * 4096, ub2 + i * 64, x);
  }

  hipMemsetAsync(pooled, 0, (size_t)(N_GRAPHS * HID + N_GRAPHS) * sizeof(float), stream);
  pool_kernel<<<(N_NODES / 64 + 1 + 3) / 4, 256, 0, stream>>>(x, batch, pooled, counts);
  gate_kernel<<<N_GRAPHS / 4, 256, 0, stream>>>(pooled, counts, mlip,
                                                gW1, gb1, gW2, gb2, gW3, gb3,
                                                (float*)d_out);
}

// Round 2
// 1018.096 us; speedup vs baseline: 1.2752x; 1.2752x over previous
//
#include <hip/hip_runtime.h>
#include <math.h>

#define N_NODES   100000
#define N_EDGES   1250000
#define HID       64
#define N_RBF     32
#define N_GRAPHS  512
#define N_EXPERTS 8
#define N_LAYERS  3
#define CUTOFF    6.0f
#define GATE_IN   72
#define G1_DIM    64
#define G2_DIM    32
#define K_TAB     4096   // lerp intervals; table has K_TAB+1 points
#define NB_SCAN   391    // ceil(N_NODES/256)

// ---------------------------------------------------------------------------
// Filter table: f_i(w) = silu(rbf(w) @ fW1[i]^T + fb1[i]) @ fW2[i]^T + fb2[i]
// 256 threads/block, 4 grid points per block (one per wave). Weights staged
// in LDS with odd padding (bank-conflict-free: stride 33 / 65).
// grid.x = N_LAYERS * 1025
// ---------------------------------------------------------------------------
__global__ __launch_bounds__(256) void build_tab(
    const float* __restrict__ fW1, const float* __restrict__ fb1,
    const float* __restrict__ fW2, const float* __restrict__ fb2,
    float* __restrict__ tab) {
  __shared__ float W1s[64][33];
  __shared__ float W2s[64][65];
  __shared__ float rbfs[4][32];
  __shared__ float h1s[4][64];
  int t = threadIdx.x;
  int wv = t >> 6, lane = t & 63;
  int layer = blockIdx.x / 1025;
  int k = (blockIdx.x % 1025) * 4 + wv;

  for (int i = t; i < 64 * 32; i += 256) W1s[i >> 5][i & 31] = fW1[layer * 2048 + i];
  for (int i = t; i < 64 * 64; i += 256) W2s[i >> 6][i & 63] = fW2[layer * 4096 + i];

  float w = (CUTOFF / (float)K_TAB) * (float)k;
  const float delta = CUTOFF / (float)(N_RBF - 1);
  const float coeff = -0.5f / (delta * delta);
  __syncthreads();

  if (lane < N_RBF) {
    float d = w - delta * (float)lane;
    rbfs[wv][lane] = expf(coeff * d * d);
  }
  __syncthreads();

  float s = fb1[layer * HID + lane];
#pragma unroll
  for (int j = 0; j < N_RBF; j++) s += rbfs[wv][j] * W1s[lane][j];
  float sig = 1.0f / (1.0f + expf(-s));
  h1s[wv][lane] = s * sig;
  __syncthreads();

  float f = fb2[layer * HID + lane];
#pragma unroll
  for (int c = 0; c < HID; c++) f += h1s[wv][c] * W2s[lane][c];
  if (k <= K_TAB) tab[(layer * (K_TAB + 1) + k) * HID + lane] = f;
}

// ---------------------------------------------------------------------------
__global__ __launch_bounds__(256) void embed_kernel(
    const int* __restrict__ z, const float* __restrict__ emb,
    float* __restrict__ x) {
  int i = blockIdx.x * 256 + threadIdx.x;
  if (i < N_NODES * HID) {
    int n = i >> 6, h = i & 63;
    x[i] = emb[z[n] * HID + h];
  }
}

// ---------------------------------------------------------------------------
// CSR build: histogram -> 2-level exclusive scan -> scatter packed records.
// rec = (src << 15) | wq, wq = round(ew * K_TAB*8/CUTOFF), clamp 32767.
// ---------------------------------------------------------------------------
__global__ __launch_bounds__(256) void hist_kernel(
    const int* __restrict__ dst, int* __restrict__ deg) {
  int e = blockIdx.x * 256 + threadIdx.x;
  if (e < N_EDGES) atomicAdd(&deg[dst[e]], 1);
}

__global__ __launch_bounds__(256) void scan1_kernel(
    const int* __restrict__ deg, int* __restrict__ bsum) {
  __shared__ int sh[256];
  int t = threadIdx.x;
  int i = blockIdx.x * 256 + t;
  sh[t] = (i < N_NODES) ? deg[i] : 0;
  __syncthreads();
  for (int off = 128; off > 0; off >>= 1) {
    if (t < off) sh[t] += sh[t + off];
    __syncthreads();
  }
  if (t == 0) bsum[blockIdx.x] = sh[0];
}

__global__ __launch_bounds__(512) void scan2_kernel(int* __restrict__ bsum) {
  __shared__ int sh[512];
  int t = threadIdx.x;
  int v = (t < NB_SCAN) ? bsum[t] : 0;
  sh[t] = v;
  __syncthreads();
  for (int off = 1; off < 512; off <<= 1) {
    int add = (t >= off) ? sh[t - off] : 0;
    __syncthreads();
    sh[t] += add;
    __syncthreads();
  }
  if (t < NB_SCAN) bsum[t] = sh[t] - v;   // exclusive
}

__global__ __launch_bounds__(256) void scan3_kernel(
    const int* __restrict__ deg, const int* __restrict__ bsum,
    int* __restrict__ rowstart, int* __restrict__ cursor) {
  __shared__ int sh[256];
  int t = threadIdx.x;
  int i = blockIdx.x * 256 + t;
  int v = (i < N_NODES) ? deg[i] : 0;
  sh[t] = v;
  __syncthreads();
  for (int off = 1; off < 256; off <<= 1) {
    int add = (t >= off) ? sh[t - off] : 0;
    __syncthreads();
    sh[t] += add;
    __syncthreads();
  }
  if (i < N_NODES) {
    int rs = bsum[blockIdx.x] + sh[t] - v;
    rowstart[i] = rs;
    cursor[i] = rs;
  }
  if (i == 0) rowstart[N_NODES] = N_EDGES;
}

__global__ __launch_bounds__(256) void scatter_kernel(
    const int* __restrict__ src, const int* __restrict__ dst,
    const float* __restrict__ ew, int* __restrict__ cursor,
    unsigned* __restrict__ recs) {
  int e = blockIdx.x * 256 + threadIdx.x;
  if (e >= N_EDGES) return;
  int d = dst[e];
  int pos = atomicAdd(&cursor[d], 1);
  float uq = ew[e] * ((float)K_TAB * 8.0f / CUTOFF);
  int wq = (int)(uq + 0.5f);
  if (wq > 32767) wq = 32767;
  recs[pos] = ((unsigned)src[e] << 15) | (unsigned)wq;
}

// ---------------------------------------------------------------------------
// y[n][o] = sum_c x[n][c] * W[o][c] + b[o]
// ---------------------------------------------------------------------------
__global__ __launch_bounds__(256) void dense64(
    const float* __restrict__ x, const float* __restrict__ W,
    const float* __restrict__ b, float* __restrict__ y) {
  __shared__ float xs[64][64];
  __shared__ float Ws[64][68];
  int t = threadIdx.x;
  int row0 = blockIdx.x * 64;

  for (int i = t; i < 4096; i += 256) Ws[i >> 6][i & 63] = W[i];
  for (int i = t; i < 4096; i += 256) {
    int r = i >> 6, gr = row0 + r;
    xs[r][i & 63] = (gr < N_NODES) ? x[gr * 64 + (i & 63)] : 0.0f;
  }
  __syncthreads();

  int l = t & 63, q = t >> 6;
  float acc[16];
  float bl = b[l];
#pragma unroll
  for (int rr = 0; rr < 16; rr++) acc[rr] = bl;
  for (int c4 = 0; c4 < 16; c4++) {
    float4 wv = *(const float4*)&Ws[l][c4 * 4];
#pragma unroll
    for (int rr = 0; rr < 16; rr++) {
      float4 xv = *(const float4*)&xs[q * 16 + rr][c4 * 4];
      acc[rr] += xv.x * wv.x + xv.y * wv.y + xv.z * wv.z + xv.w * wv.w;
    }
  }
#pragma unroll
  for (int rr = 0; rr < 16; rr++) {
    int gr = row0 + q * 16 + rr;
    if (gr < N_NODES) y[gr * 64 + l] = acc[rr];
  }
}

// ---------------------------------------------------------------------------
// x[n] += silu(agg[n] @ W1^T + b1) @ W2^T + b2
// ---------------------------------------------------------------------------
__global__ __launch_bounds__(256) void update64(
    const float* __restrict__ agg,
    const float* __restrict__ W1, const float* __restrict__ b1,
    const float* __restrict__ W2, const float* __restrict__ b2,
    float* __restrict__ x) {
  __shared__ float as[64][64];
  __shared__ float W1s[64][68];
  __shared__ float W2s[64][68];
  int t = threadIdx.x;
  int row0 = blockIdx.x * 64;

  for (int i = t; i < 4096; i += 256) {
    W1s[i >> 6][i & 63] = W1[i];
    W2s[i >> 6][i & 63] = W2[i];
  }
  for (int i = t; i < 4096; i += 256) {
    int r = i >> 6, gr = row0 + r;
    as[r][i & 63] = (gr < N_NODES) ? agg[gr * 64 + (i & 63)] : 0.0f;
  }
  __syncthreads();

  int l = t & 63, q = t >> 6;
  float acc[16];
  {
    float bl = b1[l];
#pragma unroll
    for (int rr = 0; rr < 16; rr++) acc[rr] = bl;
    for (int c4 = 0; c4 < 16; c4++) {
      float4 wv = *(const float4*)&W1s[l][c4 * 4];
#pragma unroll
      for (int rr = 0; rr < 16; rr++) {
        float4 xv = *(const float4*)&as[q * 16 + rr][c4 * 4];
        acc[rr] += xv.x * wv.x + xv.y * wv.y + xv.z * wv.z + xv.w * wv.w;
      }
    }
  }
  __syncthreads();
#pragma unroll
  for (int rr = 0; rr < 16; rr++) {
    float s = acc[rr];
    float sig = 1.0f / (1.0f + expf(-s));
    as[q * 16 + rr][l] = s * sig;
  }
  __syncthreads();
  {
    float bl = b2[l];
#pragma unroll
    for (int rr = 0; rr < 16; rr++) acc[rr] = bl;
    for (int c4 = 0; c4 < 16; c4++) {
      float4 wv = *(const float4*)&W2s[l][c4 * 4];
#pragma unroll
      for (int rr = 0; rr < 16; rr++) {
        float4 xv = *(const float4*)&as[q * 16 + rr][c4 * 4];
        acc[rr] += xv.x * wv.x + xv.y * wv.y + xv.z * wv.z + xv.w * wv.w;
      }
    }
#pragma unroll
    for (int rr = 0; rr < 16; rr++) {
      int gr = row0 + q * 16 + rr;
      if (gr < N_NODES) x[gr * 64 + l] += acc[rr];
    }
  }
}

// ---------------------------------------------------------------------------
// CSR gather: one wave per dst node. agg[d] = sum over its edges of
// y[src] * lerp(tab, w). No atomics; single coalesced write.
// ---------------------------------------------------------------------------
__global__ __launch_bounds__(256) void gather_kernel(
    const int* __restrict__ rowstart, const unsigned* __restrict__ recs,
    const float* __restrict__ tab, const float* __restrict__ y,
    float* __restrict__ agg) {
  int d = blockIdx.x * 4 + (threadIdx.x >> 6);
  int lane = threadIdx.x & 63;
  if (d >= N_NODES) return;
  int b0 = rowstart[d], b1 = rowstart[d + 1];
  float acc = 0.0f;
  // software pipeline: prefetch next record + next y value
  unsigned r = 0;
  float yv = 0.0f;
  if (b0 < b1) {
    r = recs[b0];
    yv = y[(r >> 15) * 64 + lane];
  }
  for (int j = b0; j < b1; j++) {
    unsigned rc = r;
    float yc = yv;
    if (j + 1 < b1) {
      r = recs[j + 1];
      yv = y[(r >> 15) * 64 + lane];
    }
    int wq = rc & 32767;
    int idx = wq >> 3;
    float fr = (float)(wq & 7) * 0.125f;
    float f0 = tab[idx * 64 + lane];
    float f1 = tab[idx * 64 + 64 + lane];
    acc += yc * (f0 + (f1 - f0) * fr);
  }
  agg[d * 64 + lane] = acc;
}

// ---------------------------------------------------------------------------
__global__ __launch_bounds__(256) void pool_kernel(
    const float* __restrict__ x, const int* __restrict__ batch,
    float* __restrict__ pooled, float* __restrict__ counts) {
  int wid = (blockIdx.x * 256 + threadIdx.x) >> 6;
  int lane = threadIdx.x & 63;
  int n0 = wid * 64;
  if (n0 >= N_NODES) return;
  int n1 = n0 + 64; if (n1 > N_NODES) n1 = N_NODES;
  int curg = batch[n0];
  float acc = 0.0f, cnt = 0.0f;
  for (int n = n0; n < n1; n++) {
    int g = batch[n];
    if (g != curg) {
      unsafeAtomicAdd(&pooled[curg * 64 + lane], acc);
      if (lane == 0) unsafeAtomicAdd(&counts[curg], cnt);
      curg = g; acc = 0.0f; cnt = 0.0f;
    }
    acc += x[n * 64 + lane];
    cnt += 1.0f;
  }
  unsafeAtomicAdd(&pooled[curg * 64 + lane], acc);
  if (lane == 0) unsafeAtomicAdd(&counts[curg], cnt);
}

// ---------------------------------------------------------------------------
__global__ __launch_bounds__(256) void gate_kernel(
    const float* __restrict__ pooled, const float* __restrict__ counts,
    const float* __restrict__ mlip,
    const float* __restrict__ gW1, const float* __restrict__ gb1,
    const float* __restrict__ gW2, const float* __restrict__ gb2,
    const float* __restrict__ gW3, const float* __restrict__ gb3,
    float* __restrict__ out) {
  __shared__ float ins[4][GATE_IN];
  __shared__ float h1s[4][G1_DIM];
  __shared__ float h2s[4][G2_DIM];
  __shared__ float lg[4][N_EXPERTS];
  int wv = threadIdx.x >> 6, lane = threadIdx.x & 63;
  int g = blockIdx.x * 4 + wv;

  float cnt = counts[g];
  if (cnt < 1.0f) cnt = 1.0f;
  ins[wv][lane] = pooled[g * 64 + lane] / cnt;
  if (lane < N_EXPERTS) ins[wv][64 + lane] = mlip[g * N_EXPERTS + lane];
  __syncthreads();

  {
    float s = gb1[lane];
    for (int c = 0; c < GATE_IN; c++) s += ins[wv][c] * gW1[lane * GATE_IN + c];
    h1s[wv][lane] = fmaxf(s, 0.0f);
  }
  __syncthreads();
  if (lane < G2_DIM) {
    float s = gb2[lane];
    for (int c = 0; c < G1_DIM; c++) s += h1s[wv][c] * gW2[lane * G1_DIM + c];
    h2s[wv][lane] = fmaxf(s, 0.0f);
  }
  __syncthreads();
  if (lane < N_EXPERTS) {
    float s = gb3[lane];
    for (int c = 0; c < G2_DIM; c++) s += h2s[wv][c] * gW3[lane * G2_DIM + c];
    lg[wv][lane] = s;
  }
  __syncthreads();
  if (lane < N_EXPERTS) {
    float m = -1e30f;
    for (int j = 0; j < N_EXPERTS; j++) m = fmaxf(m, lg[wv][j]);
    float den = 0.0f;
    for (int j = 0; j < N_EXPERTS; j++) den += expf(lg[wv][j] - m);
    float wgt = expf(lg[wv][lane] - m) / den;
    out[g * 8 + lane] = lg[wv][lane];
    out[N_GRAPHS * 8 + g * 8 + lane] = wgt;
    if (lane == 0) {
      float p = 0.0f;
      for (int j = 0; j < N_EXPERTS; j++)
        p += mlip[g * 8 + j] * expf(lg[wv][j] - m) / den;
      out[N_GRAPHS * 16 + g] = p;
    }
  }
}

// ---------------------------------------------------------------------------
extern "C" void kernel_launch(void* const* d_in, const int* in_sizes, int n_in,
                              void* d_out, int out_size, void* d_ws, size_t ws_size,
                              hipStream_t stream) {
  const int*   z     = (const int*)  d_in[0];
  const int*   ei    = (const int*)  d_in[1];
  const float* ew    = (const float*)d_in[2];
  const int*   batch = (const int*)  d_in[3];
  const float* mlip  = (const float*)d_in[4];
  const float* emb   = (const float*)d_in[5];
  const float* fW1   = (const float*)d_in[6];
  const float* fb1   = (const float*)d_in[7];
  const float* fW2   = (const float*)d_in[8];
  const float* fb2   = (const float*)d_in[9];
  const float* dW    = (const float*)d_in[10];
  const float* db    = (const float*)d_in[11];
  const float* uW1   = (const float*)d_in[12];
  const float* ub1   = (const float*)d_in[13];
  const float* uW2   = (const float*)d_in[14];
  const float* ub2   = (const float*)d_in[15];
  const float* gW1   = (const float*)d_in[16];
  const float* gb1   = (const float*)d_in[17];
  const float* gW2   = (const float*)d_in[18];
  const float* gb2   = (const float*)d_in[19];
  const float* gW3   = (const float*)d_in[20];
  const float* gb3   = (const float*)d_in[21];

  const int* src = ei;
  const int* dst = ei + N_EDGES;

  float* ws = (float*)d_ws;
  float*    x        = ws;                        // 6,400,000
  float*    y        = ws + 6400000;              // 6,400,000
  float*    agg      = ws + 12800000;             // 6,400,000 (aliased below)
  float*    tab      = ws + 19200000;             // 786,624
  float*    pooled   = ws + 19986624;             // 32,768
  float*    counts   = ws + 20019392;             // 512
  int*      rowstart = (int*)(ws + 20019904);     // 100,001
  unsigned* recs     = (unsigned*)(ws + 20119905);// 1,250,000 -> end 21,369,905 (85.5 MB)
  // preproc-only arrays aliased into agg's space (agg written fresh each layer)
  int* deg    = (int*)agg;
  int* cursor = deg + N_NODES;
  int* bsum   = cursor + N_NODES;                 // 391 ints

  const int EB = (N_EDGES + 255) / 256;

  // --- CSR build (once) ---
  hipMemsetAsync(deg, 0, N_NODES * sizeof(int), stream);
  hist_kernel<<<EB, 256, 0, stream>>>(dst, deg);
  scan1_kernel<<<NB_SCAN, 256, 0, stream>>>(deg, bsum);
  scan2_kernel<<<1, 512, 0, stream>>>(bsum);
  scan3_kernel<<<NB_SCAN, 256, 0, stream>>>(deg, bsum, rowstart, cursor);
  scatter_kernel<<<EB, 256, 0, stream>>>(src, dst, ew, cursor, recs);

  build_tab<<<N_LAYERS * 1025, 256, 0, stream>>>(fW1, fb1, fW2, fb2, tab);
  embed_kernel<<<(N_NODES * HID + 255) / 256, 256, 0, stream>>>(z, emb, x);

  for (int i = 0; i < N_LAYERS; i++) {
    dense64<<<(N_NODES + 63) / 64, 256, 0, stream>>>(x, dW + i * 4096, db + i * 64, y);
    gather_kernel<<<(N_NODES + 3) / 4, 256, 0, stream>>>(
        rowstart, recs, tab + i * (K_TAB + 1) * 64, y, agg);
    update64<<<(N_NODES + 63) / 64, 256, 0, stream>>>(agg, uW1 + i * 4096, ub1 + i * 64,
                                                      uW2 + i * 4096, ub2 + i * 64, x);
  }

  hipMemsetAsync(pooled, 0, (size_t)(N_GRAPHS * HID + N_GRAPHS) * sizeof(float), stream);
  pool_kernel<<<(N_NODES / 64 + 1 + 3) / 4, 256, 0, stream>>>(x, batch, pooled, counts);
  gate_kernel<<<N_GRAPHS / 4, 256, 0, stream>>>(pooled, counts, mlip,
                                                gW1, gb1, gW2, gb2, gW3, gb3,
                                                (float*)d_out);
}